// Round 23
// baseline (118.737 us; speedup 1.0000x reference)
//
#include <hip/hip_runtime.h>
#include <hip/hip_bf16.h>
#include <cstdint>
#include <cstddef>

// Causal self-attention, B=2 S=2048 E=1024 H=16 D=64.
// Inputs fp32, output fp32, ws intermediates bf16.
// Round 23: round-22 split-KV-across-blocks, crash fixed. Root cause: Pl was
// placed at byte 16MB of a 16MB d_out (OOB write -> abort). Now: split only
// qt>=17 (480 tiles): o-partials 960x8KB at [8,15.5MB), l-partials 240KB at
// 15.5MB -- all inside d_out. Max serial chain 17 iters (was 33). Kernel
// bodies identical to verified v10 path; grids 1504 (split-first) + 480 merge.

#define B_  2
#define S_  2048
#define E_  1024
#define NH_ 16
#define DH_ 64
#define M_  (B_*S_)      // 4096
#define F_  (NH_*DH_)    // 1024

typedef unsigned short u16;
typedef short short8 __attribute__((ext_vector_type(8)));
typedef float f32x4  __attribute__((ext_vector_type(4)));

#define QSCALE 0.125f

__device__ __forceinline__ float bf2f(u16 u) {
    union { unsigned int i; float f; } c; c.i = ((unsigned int)u) << 16; return c.f;
}
__device__ __forceinline__ u16 f2bf(float f) {
    union { float f; unsigned int i; } c; c.f = f;
    unsigned int x = c.i;
    x += 0x7fffu + ((x >> 16) & 1u);   // RNE
    return (u16)(x >> 16);
}

// ---------------------------------------------------------------------------
// Merged prep: [0,2048) x fp32->bf16; [2048,2816) wq/wk/wv -> bf16 [n][k];
// [2816,3072) (when launched with 3072 blocks) wo -> wot.
// ---------------------------------------------------------------------------
__global__ __launch_bounds__(256)
void prep(const float* __restrict__ x,
          const float* __restrict__ wq, const float* __restrict__ wk,
          const float* __restrict__ wv, const float* __restrict__ wo,
          u16* __restrict__ xb, u16* __restrict__ Wt, u16* __restrict__ wot)
{
    const int tid = threadIdx.x;
    const int b   = blockIdx.x;
    if (b < 2048) {
        size_t i = (size_t)b * 256 + tid;
        const float4* s = (const float4*)(x + i*8);
        float4 a = s[0], bb = s[1];
        short8 o;
        ((u16*)&o)[0] = f2bf(a.x);  ((u16*)&o)[1] = f2bf(a.y);
        ((u16*)&o)[2] = f2bf(a.z);  ((u16*)&o)[3] = f2bf(a.w);
        ((u16*)&o)[4] = f2bf(bb.x); ((u16*)&o)[5] = f2bf(bb.y);
        ((u16*)&o)[6] = f2bf(bb.z); ((u16*)&o)[7] = f2bf(bb.w);
        ((short8*)xb)[i] = o;
        return;
    }
    __shared__ u16 t[64][66];
    const int wb = b - 2048;
    const int wi = wb >> 8;
    const int tt = wb & 255;
    const int n0 = (tt & 15) * 64;
    const int k0 = (tt >> 4) * 64;
    const float* W;
    u16* dst0;
    if (wi < 3) { W = (wi == 0) ? wq : (wi == 1) ? wk : wv;
                  dst0 = Wt + (size_t)wi * E_ * F_; }
    else        { W = wo; dst0 = wot; }

    {
        int kk = tid >> 2, nseg = (tid & 3) * 16;
        const float4* src = (const float4*)(W + (size_t)(k0+kk)*F_ + n0 + nseg);
        #pragma unroll
        for (int v = 0; v < 4; ++v) {
            float4 u = src[v];
            t[kk][nseg + v*4 + 0] = f2bf(u.x);
            t[kk][nseg + v*4 + 1] = f2bf(u.y);
            t[kk][nseg + v*4 + 2] = f2bf(u.z);
            t[kk][nseg + v*4 + 3] = f2bf(u.w);
        }
    }
    __syncthreads();
    {
        int nn = tid >> 2, kseg = (tid & 3) * 16;
        short8 o0, o1;
        #pragma unroll
        for (int i = 0; i < 8; ++i) ((u16*)&o0)[i] = t[kseg + i][nn];
        #pragma unroll
        for (int i = 0; i < 8; ++i) ((u16*)&o1)[i] = t[kseg + 8 + i][nn];
        u16* dst = dst0 + (size_t)(n0+nn)*E_ + k0 + kseg;
        ((short8*)dst)[0] = o0;
        ((short8*)dst)[1] = o1;
    }
}

// ---------------------------------------------------------------------------
// Standalone W transpose (fallback for wo when ws is small).
// ---------------------------------------------------------------------------
__global__ __launch_bounds__(256)
void wtrans(const float* __restrict__ W, u16* __restrict__ Wt)
{
    __shared__ u16 t[64][66];
    const int tid = threadIdx.x;
    const int n0 = blockIdx.x * 64;
    const int k0 = blockIdx.y * 64;
    {
        int kk = tid >> 2, nseg = (tid & 3) * 16;
        const float4* src = (const float4*)(W + (size_t)(k0+kk)*F_ + n0 + nseg);
        #pragma unroll
        for (int v = 0; v < 4; ++v) {
            float4 u = src[v];
            t[kk][nseg + v*4 + 0] = f2bf(u.x);
            t[kk][nseg + v*4 + 1] = f2bf(u.y);
            t[kk][nseg + v*4 + 2] = f2bf(u.z);
            t[kk][nseg + v*4 + 3] = f2bf(u.w);
        }
    }
    __syncthreads();
    {
        int nn = tid >> 2, kseg = (tid & 3) * 16;
        short8 o0, o1;
        #pragma unroll
        for (int i = 0; i < 8; ++i) ((u16*)&o0)[i] = t[kseg + i][nn];
        #pragma unroll
        for (int i = 0; i < 8; ++i) ((u16*)&o1)[i] = t[kseg + 8 + i][nn];
        u16* dst = Wt + (size_t)(n0+nn)*E_ + k0 + kseg;
        ((short8*)dst)[0] = o0;
        ((short8*)dst)[1] = o1;
    }
}

// ---------------------------------------------------------------------------
// bf16 MFMA GEMM via global_load_lds. BM=128, BN=64, BK=64, 4 waves.
// MODE 0: grid 1536; MODE 2: grid 512. XCD-local decode. (unchanged)
// ---------------------------------------------------------------------------
template<int MODE>
__global__ __launch_bounds__(256)
void gemm_bf16(const u16* __restrict__ A, const u16* __restrict__ Wt,
               void* __restrict__ Out0, void* __restrict__ Out1,
               void* __restrict__ Out2)
{
    __shared__ __align__(16) char lds[24576];
    char* lA = lds;
    char* lB = lds + 16384;

    const int tid  = threadIdx.x;
    const int lane = tid & 63;
    const int w    = tid >> 6;
    const int wr   = w >> 1, wc = w & 1;
    const int g    = lane >> 4;
    const int q15  = lane & 15;

    const int lin = blockIdx.x;
    const int j   = lin >> 3, xc = lin & 7;
    const int bx  = ((xc >> 2) << 3) + (j & 7);
    const int by  = ((xc & 3) << 3) + ((j >> 3) & 7);
    const int z   = j >> 6;

    const u16* Wz  = Wt + (size_t)z * E_ * F_;
    void*      Out = (z == 0) ? Out0 : (z == 1) ? Out1 : Out2;
    const float osc = (MODE == 0 && z == 0) ? QSCALE : 1.0f;

    const int lr  = lane >> 3;
    const int lc  = lane & 7;
    const int swz = ((lc ^ lr) << 4);

    const int b2 = by >> 4;
    const int s0 = (by & 15) * 128;

    f32x4 acc[4][2];
    #pragma unroll
    for (int i = 0; i < 4; ++i)
        #pragma unroll
        for (int jj = 0; jj < 2; ++jj) acc[i][jj] = (f32x4){0.f,0.f,0.f,0.f};

    for (int it = 0; it < E_/64; ++it) {
        const int k0 = it * 64;
        __syncthreads();
        #pragma unroll
        for (int i = 0; i < 4; ++i) {
            const int row = w*32 + i*8 + lr;
            const char* ga;
            if (MODE == 0) {
                ga = (const char*)A + (size_t)(by*128 + row)*2048 + k0*2 + swz;
            } else {
                const int h = k0 >> 6;
                ga = (const char*)A +
                     ((size_t)(b2*NH_ + h)*S_ + s0 + row)*128 + swz;
            }
            __builtin_amdgcn_global_load_lds(
                (const unsigned int*)ga,
                (unsigned int*)(lA + w*4096 + i*1024), 16, 0, 0);
        }
        #pragma unroll
        for (int i = 0; i < 2; ++i) {
            const int row = w*16 + i*8 + lr;
            const char* gb = (const char*)Wz + (size_t)(bx*64 + row)*2048
                             + k0*2 + swz;
            __builtin_amdgcn_global_load_lds(
                (const unsigned int*)gb,
                (unsigned int*)(lB + w*2048 + i*1024), 16, 0, 0);
        }
        __syncthreads();

        #pragma unroll
        for (int s = 0; s < 2; ++s) {
            short8 af[4], bfr[2];
            #pragma unroll
            for (int mt = 0; mt < 4; ++mt) {
                int row = wr*64 + mt*16 + q15;
                af[mt] = *(const short8*)(lA + row*128 + ((s*64 + 16*g) ^ ((row&7)<<4)));
            }
            #pragma unroll
            for (int nt = 0; nt < 2; ++nt) {
                int n = wc*32 + nt*16 + q15;
                bfr[nt] = *(const short8*)(lB + n*128 + ((s*64 + 16*g) ^ ((n&7)<<4)));
            }
            #pragma unroll
            for (int mt = 0; mt < 4; ++mt)
                #pragma unroll
                for (int nt = 0; nt < 2; ++nt)
                    acc[mt][nt] = __builtin_amdgcn_mfma_f32_16x16x32_bf16(
                        af[mt], bfr[nt], acc[mt][nt], 0, 0, 0);
        }
    }

    #pragma unroll
    for (int mt = 0; mt < 4; ++mt) {
        #pragma unroll
        for (int r = 0; r < 4; ++r) {
            int grow = by*128 + wr*64 + mt*16 + 4*g + r;
            if (MODE == 0) {
                int bb = grow >> 11, ss = grow & (S_-1);
                #pragma unroll
                for (int nt = 0; nt < 2; ++nt) {
                    int n = bx*64 + wc*32 + nt*16 + q15;
                    int hh = n >> 6, dd = n & 63;
                    ((u16*)Out)[(((size_t)bb*NH_ + hh)*S_ + ss)*DH_ + dd] =
                        f2bf(acc[mt][nt][r] * osc);
                }
            } else {
                #pragma unroll
                for (int nt = 0; nt < 2; ++nt) {
                    int n = bx*64 + wc*32 + nt*16 + q15;
                    ((float*)Out)[(size_t)grow * F_ + n] = acc[mt][nt][r];
                }
            }
        }
    }
}

// ---------------------------------------------------------------------------
// V transpose: [b][h][s][d] -> Vt [b][h][d][s] (unchanged, verified).
// ---------------------------------------------------------------------------
__global__ __launch_bounds__(256)
void vtrans(const u16* __restrict__ V, u16* __restrict__ Vt)
{
    __shared__ u16 t[64][66];
    const int tid = threadIdx.x;
    const int st  = blockIdx.x;
    const int bh  = blockIdx.y;

    {
        int s = tid >> 2, dseg = (tid & 3) * 16;
        const u16* src = V + ((size_t)bh*S_ + st*64 + s)*DH_ + dseg;
        short8 a = ((const short8*)src)[0];
        short8 b = ((const short8*)src)[1];
        *(short8*)&t[s][dseg]     = a;
        *(short8*)&t[s][dseg + 8] = b;
    }
    __syncthreads();
    {
        int d = tid >> 2, sseg = (tid & 3) * 16;
        short8 o0, o1;
        #pragma unroll
        for (int i = 0; i < 8; ++i) ((u16*)&o0)[i] = t[sseg + i][d];
        #pragma unroll
        for (int i = 0; i < 8; ++i) ((u16*)&o1)[i] = t[sseg + 8 + i][d];
        u16* dst = Vt + ((size_t)bh*DH_ + d)*S_ + st*64 + sseg;
        ((short8*)dst)[0] = o0;
        ((short8*)dst)[1] = o1;
    }
}

// ---------------------------------------------------------------------------
// attn_v13: v10 body; block processes kv tiles [kstart, kstart+kcnt) of
// q-tile qt. Tiles qt>=17 split into two blocks (write bf16 o-partial +
// fp32 l to scratch); others write O directly. Split blocks dispatch first.
// ---------------------------------------------------------------------------
__global__ __launch_bounds__(256)
void attn_v13(const u16* Q, const u16* __restrict__ K,
              const u16* __restrict__ Vt, u16* O,
              u16* __restrict__ Po, float* __restrict__ Pl)
{
    __shared__ __align__(16) char vls[2*8192];
    __shared__ __align__(16) char kls[2*8192];

    const int tid  = threadIdx.x;
    const int lane = tid & 63;
    const int w    = tid >> 6;
    const int g    = lane >> 4;
    const int q15  = lane & 15;

    const int blk = blockIdx.x;
    int qt, bh, kstart, kcnt, pidx;
    if (blk < 960) {                     // split halves of tiles qt>=17
        int ab = blk & 1, s = blk >> 1;  // s in [0,480)
        qt = 17 + (s >> 5); bh = s & 31;
        int nA = (qt + 2) >> 1;
        kstart = ab ? nA : 0;
        kcnt   = ab ? (qt + 1 - nA) : nA;
        pidx   = ((qt - 17) * 32 + bh) * 2 + ab;
    } else {
        int s = blk - 960;               // s in [0,544)
        qt = s >> 5; bh = s & 31;        // qt in [0,16]
        kstart = 0; kcnt = qt + 1; pidx = -1;
    }
    const int q0 = qt * 64;

    const u16* Kb  = K  + (size_t)bh * S_ * DH_;
    const u16* Vtb = Vt + (size_t)bh * DH_ * S_;

    short8 qf0, qf1;
    {
        const u16* Qp = Q + ((size_t)bh * S_ + q0 + w*16 + q15) * DH_ + g*8;
        qf0 = *(const short8*)(Qp);
        qf1 = *(const short8*)(Qp + 32);
    }

    f32x4 o[4];
    #pragma unroll
    for (int dt = 0; dt < 4; ++dt) o[dt] = (f32x4){0.f,0.f,0.f,0.f};
    float lrow = 0.f;

    const int sd = tid >> 2;
    const int sk = (tid & 3) * 32;

    short8 svv0, svv1, svk0, svk1;
    auto LOADX = [&](int t) {
        const u16* vs = Vtb + (size_t)sd * S_ + t*64 + (sk >> 1);
        svv0 = ((const short8*)vs)[0];
        svv1 = ((const short8*)vs)[1];
        const u16* ks = Kb + (size_t)(t*64 + sd) * DH_ + (sk >> 1);
        svk0 = ((const short8*)ks)[0];
        svk1 = ((const short8*)ks)[1];
    };
    auto WRITEX = [&](int buf) {
        char* vdst = vls + buf*8192 + sd*128;
        *(short8*)(vdst + ((sk     ) ^ ((sd&7)<<4))) = svv0;
        *(short8*)(vdst + ((sk + 16) ^ ((sd&7)<<4))) = svv1;
        char* kdst = kls + buf*8192 + sd*128;
        *(short8*)(kdst + ((sk     ) ^ ((sd&7)<<4))) = svk0;
        *(short8*)(kdst + ((sk + 16) ^ ((sd&7)<<4))) = svk1;
    };

    LOADX(kstart);
    WRITEX(0);
    __syncthreads();

    for (int i = 0; ; ++i) {
        const int kt = kstart + i;
        const bool more = (i + 1 < kcnt);
        if (more) LOADX(kt + 1);

        const int cur = i & 1;
        const char* kt_ = kls + cur * 8192;
        const char* vt_ = vls + cur * 8192;
        char* plw = kls + (cur ^ 1) * 8192 + w * 2048;

        float p[16];
        __builtin_amdgcn_s_setprio(1);
        #pragma unroll
        for (int t = 0; t < 4; ++t) {
            int r = t*16 + q15;
            short8 kf0 = *(const short8*)(kt_ + r*128 + ((16*g     ) ^ ((r&7)<<4)));
            short8 kf1 = *(const short8*)(kt_ + r*128 + ((16*g + 64) ^ ((r&7)<<4)));
            f32x4 st = (f32x4){0.f,0.f,0.f,0.f};
            st = __builtin_amdgcn_mfma_f32_16x16x32_bf16(kf0, qf0, st, 0, 0, 0);
            st = __builtin_amdgcn_mfma_f32_16x16x32_bf16(kf1, qf1, st, 0, 0, 0);
            #pragma unroll
            for (int r2 = 0; r2 < 4; ++r2) p[t*4+r2] = st[r2];
        }
        __builtin_amdgcn_s_setprio(0);

        if (kt == qt) {
            #pragma unroll
            for (int t = 0; t < 4; ++t)
                #pragma unroll
                for (int r = 0; r < 4; ++r)
                    if (16*t + 4*g + r > w*16 + q15) p[t*4+r] = -1e30f;
        }

        float psum = 0.f;
        #pragma unroll
        for (int i2 = 0; i2 < 16; ++i2) { p[i2] = __expf(p[i2]); psum += p[i2]; }
        psum += __shfl_xor(psum, 16);
        psum += __shfl_xor(psum, 32);
        lrow += psum;

        #pragma unroll
        for (int t = 0; t < 4; ++t) {
            unsigned r0, r1;
            asm("v_cvt_pk_bf16_f32 %0, %1, %2"
                : "=v"(r0) : "v"(p[t*4+0]), "v"(p[t*4+1]));
            asm("v_cvt_pk_bf16_f32 %0, %1, %2"
                : "=v"(r1) : "v"(p[t*4+2]), "v"(p[t*4+3]));
            int byte = q15*128 + ((32*t + 8*g) ^ ((q15&7)<<4));
            uint2 pk; pk.x = r0; pk.y = r1;
            *(uint2*)(plw + byte) = pk;
        }

        __builtin_amdgcn_s_setprio(1);
        #pragma unroll
        for (int c = 0; c < 2; ++c) {
            int pb = q15*128 + ((64*c + 16*g) ^ ((q15&7)<<4));
            short8 pf = *(const short8*)(plw + pb);
            #pragma unroll
            for (int dt = 0; dt < 4; ++dt) {
                int d = dt*16 + q15;
                int vb = d*128 + ((64*c + 16*g) ^ ((d&7)<<4));
                short8 vf = *(const short8*)(vt_ + vb);
                o[dt] = __builtin_amdgcn_mfma_f32_16x16x32_bf16(pf, vf, o[dt], 0, 0, 0);
            }
        }
        __builtin_amdgcn_s_setprio(0);

        if (!more) break;
        WRITEX((i + 1) & 1);
        __syncthreads();
    }

    if (pidx >= 0) {
        u16*   po = Po + (size_t)pidx * 4096;
        float* pl = Pl + pidx * 64;
        #pragma unroll
        for (int r = 0; r < 4; ++r) {
            int ql = w*16 + 4*g + r;
            #pragma unroll
            for (int dt = 0; dt < 4; ++dt)
                po[ql*64 + dt*16 + q15] = f2bf(o[dt][r]);
        }
        if (g == 0) pl[w*16 + q15] = lrow;
    } else {
        float inv = 1.f / lrow;
        #pragma unroll
        for (int r = 0; r < 4; ++r) {
            float li = __shfl(inv, 4*g + r);
            int qrow = q0 + w*16 + 4*g + r;
            #pragma unroll
            for (int dt = 0; dt < 4; ++dt) {
                O[((size_t)bh * S_ + qrow) * DH_ + dt*16 + q15] =
                    f2bf(o[dt][r] * li);
            }
        }
    }
}

// ---------------------------------------------------------------------------
// merge_attn: one block per split (qt,bh): O = (oA+oB)/(lA+lB) -> Qw rows.
// ---------------------------------------------------------------------------
__global__ __launch_bounds__(256)
void merge_attn(const u16* __restrict__ Po, const float* __restrict__ Pl,
                u16* __restrict__ O)
{
    const int blk = blockIdx.x;            // 480 = (qt-17)*32 + bh
    const int qt  = 17 + (blk >> 5);
    const int bh  = blk & 31;
    const int base = blk * 2;
    const u16*   oA = Po + (size_t)base * 4096;
    const u16*   oB = oA + 4096;
    const float* lA = Pl + base * 64;
    const float* lB = lA + 64;

    const int q  = threadIdx.x >> 2;
    const int d0 = (threadIdx.x & 3) * 16;
    const float linv = 1.f / (lA[q] + lB[q]);

    const short8* a = (const short8*)(oA + q*64 + d0);
    const short8* b = (const short8*)(oB + q*64 + d0);
    u16* dst = O + ((size_t)bh * S_ + qt*64 + q) * DH_ + d0;
    #pragma unroll
    for (int j = 0; j < 2; ++j) {
        short8 av = a[j], bv = b[j];
        short8 ov;
        #pragma unroll
        for (int k = 0; k < 8; ++k)
            ((u16*)&ov)[k] = f2bf((bf2f(((const u16*)&av)[k]) +
                                   bf2f(((const u16*)&bv)[k])) * linv);
        ((short8*)dst)[j] = ov;
    }
}

// ---------------------------------------------------------------------------
// Scratch: ws = Qw|Kw|Vw (24 MiB) [+ wo^T at 24MB if ws_size allows];
// d_out (16 MiB): [0..8MB) Wt_qkv then Vt; [8..15.5MB) xb then o-partials;
// [15.5..15.73MB) l-partials. Final oproj overwrites all of d_out.
// ---------------------------------------------------------------------------
extern "C" void kernel_launch(void* const* d_in, const int* in_sizes, int n_in,
                              void* d_out, int out_size, void* d_ws, size_t ws_size,
                              hipStream_t stream) {
    (void)in_sizes; (void)n_in; (void)out_size;
    const float* x  = (const float*)d_in[0];
    const float* wq = (const float*)d_in[1];
    const float* wk = (const float*)d_in[2];
    const float* wv = (const float*)d_in[3];
    const float* wo = (const float*)d_in[4];

    u16* Qw = (u16*)d_ws;
    u16* Kw = Qw + (size_t)M_ * F_;
    u16* Vw = Kw + (size_t)M_ * F_;

    u16*   D0 = (u16*)d_out;
    u16*   xb = D0 + (size_t)4*1024*1024;                    // byte 8MB
    u16*   Po = xb;                                          // 960 x 8KB = 7.5MB
    float* Pl = (float*)((char*)d_out +
                 ((size_t)8 << 20) + (size_t)960 * 8192);    // byte 16,252,928

    const bool bigws = ws_size >= ((size_t)27 << 20);
    u16* wot = bigws ? (u16*)((char*)d_ws + ((size_t)24 << 20)) : Vw;

    prep<<<dim3(bigws ? 3072 : 2816), 256, 0, stream>>>(
        x, wq, wk, wv, wo, xb, D0, wot);

    gemm_bf16<0><<<dim3(1536), 256, 0, stream>>>(
        xb, D0, (void*)Qw, (void*)Kw, (void*)Vw);

    vtrans<<<dim3(S_/64, B_*NH_), 256, 0, stream>>>(Vw, D0);
    if (!bigws)
        wtrans<<<dim3(16,16), 256, 0, stream>>>(wo, Vw);

    attn_v13<<<dim3(1504), 256, 0, stream>>>(Qw, Kw, D0, Qw, Po, Pl);
    merge_attn<<<dim3(480), 256, 0, stream>>>(Po, Pl, Qw);

    gemm_bf16<2><<<dim3(512), 256, 0, stream>>>(
        Qw, wot, d_out, d_out, d_out);
}

// Round 24
// 113.278 us; speedup vs baseline: 1.0482x; 1.0482x over previous
//
#include <hip/hip_runtime.h>
#include <hip/hip_bf16.h>
#include <cstdint>
#include <cstddef>

// Causal self-attention, B=2 S=2048 E=1024 H=16 D=64.
// Inputs fp32, output fp32, ws intermediates bf16.
// Round 24: REVERT to round-19 exact configuration (best measured: 113.8us).
// Round 22/23's cross-block split-KV proved the drain-tail theory wrong
// (attn invariant at 45us across 6 scheduling variants -> bound by the
// within-iteration dependency chain), and its merge pass cost ~5us net.
// Pipeline: prep (x->bf16 + W^T) -> qkv GEMM (BN=64, XCD-local) -> vtrans
// -> attn_v10 (LPT, max-free softmax, P in dead K-buffer, cross-iter
// pipeline) -> oproj GEMM (BN=64).

#define B_  2
#define S_  2048
#define E_  1024
#define NH_ 16
#define DH_ 64
#define M_  (B_*S_)      // 4096
#define F_  (NH_*DH_)    // 1024

typedef unsigned short u16;
typedef short short8 __attribute__((ext_vector_type(8)));
typedef float f32x4  __attribute__((ext_vector_type(4)));

#define QSCALE 0.125f

__device__ __forceinline__ u16 f2bf(float f) {
    union { float f; unsigned int i; } c; c.f = f;
    unsigned int x = c.i;
    x += 0x7fffu + ((x >> 16) & 1u);   // RNE
    return (u16)(x >> 16);
}

// ---------------------------------------------------------------------------
// Merged prep: [0,2048) x fp32->bf16; [2048,2816) wq/wk/wv -> bf16 [n][k];
// [2816,3072) (when launched with 3072 blocks) wo -> wot.
// ---------------------------------------------------------------------------
__global__ __launch_bounds__(256)
void prep(const float* __restrict__ x,
          const float* __restrict__ wq, const float* __restrict__ wk,
          const float* __restrict__ wv, const float* __restrict__ wo,
          u16* __restrict__ xb, u16* __restrict__ Wt, u16* __restrict__ wot)
{
    const int tid = threadIdx.x;
    const int b   = blockIdx.x;
    if (b < 2048) {
        size_t i = (size_t)b * 256 + tid;
        const float4* s = (const float4*)(x + i*8);
        float4 a = s[0], bb = s[1];
        short8 o;
        ((u16*)&o)[0] = f2bf(a.x);  ((u16*)&o)[1] = f2bf(a.y);
        ((u16*)&o)[2] = f2bf(a.z);  ((u16*)&o)[3] = f2bf(a.w);
        ((u16*)&o)[4] = f2bf(bb.x); ((u16*)&o)[5] = f2bf(bb.y);
        ((u16*)&o)[6] = f2bf(bb.z); ((u16*)&o)[7] = f2bf(bb.w);
        ((short8*)xb)[i] = o;
        return;
    }
    __shared__ u16 t[64][66];
    const int wb = b - 2048;
    const int wi = wb >> 8;            // 0..2 = q/k/v, 3 = wo
    const int tt = wb & 255;
    const int n0 = (tt & 15) * 64;
    const int k0 = (tt >> 4) * 64;
    const float* W;
    u16* dst0;
    if (wi < 3) { W = (wi == 0) ? wq : (wi == 1) ? wk : wv;
                  dst0 = Wt + (size_t)wi * E_ * F_; }
    else        { W = wo; dst0 = wot; }

    {
        int kk = tid >> 2, nseg = (tid & 3) * 16;
        const float4* src = (const float4*)(W + (size_t)(k0+kk)*F_ + n0 + nseg);
        #pragma unroll
        for (int v = 0; v < 4; ++v) {
            float4 u = src[v];
            t[kk][nseg + v*4 + 0] = f2bf(u.x);
            t[kk][nseg + v*4 + 1] = f2bf(u.y);
            t[kk][nseg + v*4 + 2] = f2bf(u.z);
            t[kk][nseg + v*4 + 3] = f2bf(u.w);
        }
    }
    __syncthreads();
    {
        int nn = tid >> 2, kseg = (tid & 3) * 16;
        short8 o0, o1;
        #pragma unroll
        for (int i = 0; i < 8; ++i) ((u16*)&o0)[i] = t[kseg + i][nn];
        #pragma unroll
        for (int i = 0; i < 8; ++i) ((u16*)&o1)[i] = t[kseg + 8 + i][nn];
        u16* dst = dst0 + (size_t)(n0+nn)*E_ + k0 + kseg;
        ((short8*)dst)[0] = o0;
        ((short8*)dst)[1] = o1;
    }
}

// ---------------------------------------------------------------------------
// Standalone W transpose (fallback for wo when ws is small).
// ---------------------------------------------------------------------------
__global__ __launch_bounds__(256)
void wtrans(const float* __restrict__ W, u16* __restrict__ Wt)
{
    __shared__ u16 t[64][66];
    const int tid = threadIdx.x;
    const int n0 = blockIdx.x * 64;
    const int k0 = blockIdx.y * 64;
    {
        int kk = tid >> 2, nseg = (tid & 3) * 16;
        const float4* src = (const float4*)(W + (size_t)(k0+kk)*F_ + n0 + nseg);
        #pragma unroll
        for (int v = 0; v < 4; ++v) {
            float4 u = src[v];
            t[kk][nseg + v*4 + 0] = f2bf(u.x);
            t[kk][nseg + v*4 + 1] = f2bf(u.y);
            t[kk][nseg + v*4 + 2] = f2bf(u.z);
            t[kk][nseg + v*4 + 3] = f2bf(u.w);
        }
    }
    __syncthreads();
    {
        int nn = tid >> 2, kseg = (tid & 3) * 16;
        short8 o0, o1;
        #pragma unroll
        for (int i = 0; i < 8; ++i) ((u16*)&o0)[i] = t[kseg + i][nn];
        #pragma unroll
        for (int i = 0; i < 8; ++i) ((u16*)&o1)[i] = t[kseg + 8 + i][nn];
        u16* dst = Wt + (size_t)(n0+nn)*E_ + k0 + kseg;
        ((short8*)dst)[0] = o0;
        ((short8*)dst)[1] = o1;
    }
}

// ---------------------------------------------------------------------------
// bf16 MFMA GEMM via global_load_lds. BM=128, BN=64, BK=64, 4 waves.
// MODE 0: grid 1536 = 16bx*32by*3z; A = xb rows, scatter-out bf16 (head=bx).
// MODE 2: grid  512 = 16bx*32by;    A = O gather,  row-major fp32 out.
// XCD-local decode: cell = 8bx x 8by (x3z).
// ---------------------------------------------------------------------------
template<int MODE>
__global__ __launch_bounds__(256)
void gemm_bf16(const u16* __restrict__ A, const u16* __restrict__ Wt,
               void* __restrict__ Out0, void* __restrict__ Out1,
               void* __restrict__ Out2)
{
    __shared__ __align__(16) char lds[24576];
    char* lA = lds;            // 128 rows * 128 B
    char* lB = lds + 16384;    // 64 n * 128 B

    const int tid  = threadIdx.x;
    const int lane = tid & 63;
    const int w    = tid >> 6;
    const int wr   = w >> 1, wc = w & 1;
    const int g    = lane >> 4;
    const int q15  = lane & 15;

    const int lin = blockIdx.x;
    const int j   = lin >> 3, xc = lin & 7;
    const int bx  = ((xc >> 2) << 3) + (j & 7);          // [0,16)
    const int by  = ((xc & 3) << 3) + ((j >> 3) & 7);    // [0,32)
    const int z   = j >> 6;                              // [0,3) M0; 0 M2

    const u16* Wz  = Wt + (size_t)z * E_ * F_;
    void*      Out = (z == 0) ? Out0 : (z == 1) ? Out1 : Out2;
    const float osc = (MODE == 0 && z == 0) ? QSCALE : 1.0f;

    const int lr  = lane >> 3;
    const int lc  = lane & 7;
    const int swz = ((lc ^ lr) << 4);

    const int b2 = by >> 4;
    const int s0 = (by & 15) * 128;

    f32x4 acc[4][2];
    #pragma unroll
    for (int i = 0; i < 4; ++i)
        #pragma unroll
        for (int jj = 0; jj < 2; ++jj) acc[i][jj] = (f32x4){0.f,0.f,0.f,0.f};

    for (int it = 0; it < E_/64; ++it) {
        const int k0 = it * 64;
        __syncthreads();
        #pragma unroll
        for (int i = 0; i < 4; ++i) {
            const int row = w*32 + i*8 + lr;
            const char* ga;
            if (MODE == 0) {
                ga = (const char*)A + (size_t)(by*128 + row)*2048 + k0*2 + swz;
            } else {
                const int h = k0 >> 6;
                ga = (const char*)A +
                     ((size_t)(b2*NH_ + h)*S_ + s0 + row)*128 + swz;
            }
            __builtin_amdgcn_global_load_lds(
                (const unsigned int*)ga,
                (unsigned int*)(lA + w*4096 + i*1024), 16, 0, 0);
        }
        #pragma unroll
        for (int i = 0; i < 2; ++i) {
            const int row = w*16 + i*8 + lr;
            const char* gb = (const char*)Wz + (size_t)(bx*64 + row)*2048
                             + k0*2 + swz;
            __builtin_amdgcn_global_load_lds(
                (const unsigned int*)gb,
                (unsigned int*)(lB + w*2048 + i*1024), 16, 0, 0);
        }
        __syncthreads();

        #pragma unroll
        for (int s = 0; s < 2; ++s) {
            short8 af[4], bfr[2];
            #pragma unroll
            for (int mt = 0; mt < 4; ++mt) {
                int row = wr*64 + mt*16 + q15;
                af[mt] = *(const short8*)(lA + row*128 + ((s*64 + 16*g) ^ ((row&7)<<4)));
            }
            #pragma unroll
            for (int nt = 0; nt < 2; ++nt) {
                int n = wc*32 + nt*16 + q15;
                bfr[nt] = *(const short8*)(lB + n*128 + ((s*64 + 16*g) ^ ((n&7)<<4)));
            }
            #pragma unroll
            for (int mt = 0; mt < 4; ++mt)
                #pragma unroll
                for (int nt = 0; nt < 2; ++nt)
                    acc[mt][nt] = __builtin_amdgcn_mfma_f32_16x16x32_bf16(
                        af[mt], bfr[nt], acc[mt][nt], 0, 0, 0);
        }
    }

    #pragma unroll
    for (int mt = 0; mt < 4; ++mt) {
        #pragma unroll
        for (int r = 0; r < 4; ++r) {
            int grow = by*128 + wr*64 + mt*16 + 4*g + r;
            if (MODE == 0) {
                int bb = grow >> 11, ss = grow & (S_-1);
                #pragma unroll
                for (int nt = 0; nt < 2; ++nt) {
                    int n = bx*64 + wc*32 + nt*16 + q15;
                    int hh = n >> 6, dd = n & 63;
                    ((u16*)Out)[(((size_t)bb*NH_ + hh)*S_ + ss)*DH_ + dd] =
                        f2bf(acc[mt][nt][r] * osc);
                }
            } else {
                #pragma unroll
                for (int nt = 0; nt < 2; ++nt) {
                    int n = bx*64 + wc*32 + nt*16 + q15;
                    ((float*)Out)[(size_t)grow * F_ + n] = acc[mt][nt][r];
                }
            }
        }
    }
}

// ---------------------------------------------------------------------------
// V transpose: [b][h][s][d] -> Vt [b][h][d][s] (unchanged, verified).
// ---------------------------------------------------------------------------
__global__ __launch_bounds__(256)
void vtrans(const u16* __restrict__ V, u16* __restrict__ Vt)
{
    __shared__ u16 t[64][66];
    const int tid = threadIdx.x;
    const int st  = blockIdx.x;
    const int bh  = blockIdx.y;

    {
        int s = tid >> 2, dseg = (tid & 3) * 16;
        const u16* src = V + ((size_t)bh*S_ + st*64 + s)*DH_ + dseg;
        short8 a = ((const short8*)src)[0];
        short8 b = ((const short8*)src)[1];
        *(short8*)&t[s][dseg]     = a;
        *(short8*)&t[s][dseg + 8] = b;
    }
    __syncthreads();
    {
        int d = tid >> 2, sseg = (tid & 3) * 16;
        short8 o0, o1;
        #pragma unroll
        for (int i = 0; i < 8; ++i) ((u16*)&o0)[i] = t[sseg + i][d];
        #pragma unroll
        for (int i = 0; i < 8; ++i) ((u16*)&o1)[i] = t[sseg + 8 + i][d];
        u16* dst = Vt + ((size_t)bh*DH_ + d)*S_ + st*64 + sseg;
        ((short8*)dst)[0] = o0;
        ((short8*)dst)[1] = o1;
    }
}

// ---------------------------------------------------------------------------
// attn_v10 (verified best): max-free softmax, P in dead K-buffer,
// cross-iteration pipeline, LPT order.
// ---------------------------------------------------------------------------
__global__ __launch_bounds__(256)
void attn_v10(const u16* Q, const u16* __restrict__ K,
              const u16* __restrict__ Vt, u16* O)
{
    __shared__ __align__(16) char vls[2*8192];
    __shared__ __align__(16) char kls[2*8192];

    const int tid  = threadIdx.x;
    const int lane = tid & 63;
    const int w    = tid >> 6;
    const int g    = lane >> 4;
    const int q15  = lane & 15;

    const int blk = blockIdx.x;
    const int qg  = 31 - (blk >> 5);
    const int bh  = blk & 31;
    const int q0  = qg * 64;

    const u16* Kb  = K  + (size_t)bh * S_ * DH_;
    const u16* Vtb = Vt + (size_t)bh * DH_ * S_;

    short8 qf0, qf1;
    {
        const u16* Qp = Q + ((size_t)bh * S_ + q0 + w*16 + q15) * DH_ + g*8;
        qf0 = *(const short8*)(Qp);
        qf1 = *(const short8*)(Qp + 32);
    }

    f32x4 o[4];
    #pragma unroll
    for (int dt = 0; dt < 4; ++dt) o[dt] = (f32x4){0.f,0.f,0.f,0.f};
    float lrow = 0.f;

    const int sd = tid >> 2;
    const int sk = (tid & 3) * 32;

    short8 svv0, svv1, svk0, svk1;
    auto LOADX = [&](int t) {
        const u16* vs = Vtb + (size_t)sd * S_ + t*64 + (sk >> 1);
        svv0 = ((const short8*)vs)[0];
        svv1 = ((const short8*)vs)[1];
        const u16* ks = Kb + (size_t)(t*64 + sd) * DH_ + (sk >> 1);
        svk0 = ((const short8*)ks)[0];
        svk1 = ((const short8*)ks)[1];
    };
    auto WRITEX = [&](int buf) {
        char* vdst = vls + buf*8192 + sd*128;
        *(short8*)(vdst + ((sk     ) ^ ((sd&7)<<4))) = svv0;
        *(short8*)(vdst + ((sk + 16) ^ ((sd&7)<<4))) = svv1;
        char* kdst = kls + buf*8192 + sd*128;
        *(short8*)(kdst + ((sk     ) ^ ((sd&7)<<4))) = svk0;
        *(short8*)(kdst + ((sk + 16) ^ ((sd&7)<<4))) = svk1;
    };

    LOADX(0);
    WRITEX(0);
    __syncthreads();

    for (int kt = 0; ; ++kt) {
        const bool more = (kt < qg);
        if (more) LOADX(kt + 1);

        const int cur = kt & 1;
        const char* kt_ = kls + cur * 8192;
        const char* vt_ = vls + cur * 8192;
        char* plw = kls + (cur ^ 1) * 8192 + w * 2048;

        float p[16];
        __builtin_amdgcn_s_setprio(1);
        #pragma unroll
        for (int t = 0; t < 4; ++t) {
            int r = t*16 + q15;
            short8 kf0 = *(const short8*)(kt_ + r*128 + ((16*g     ) ^ ((r&7)<<4)));
            short8 kf1 = *(const short8*)(kt_ + r*128 + ((16*g + 64) ^ ((r&7)<<4)));
            f32x4 st = (f32x4){0.f,0.f,0.f,0.f};
            st = __builtin_amdgcn_mfma_f32_16x16x32_bf16(kf0, qf0, st, 0, 0, 0);
            st = __builtin_amdgcn_mfma_f32_16x16x32_bf16(kf1, qf1, st, 0, 0, 0);
            #pragma unroll
            for (int r2 = 0; r2 < 4; ++r2) p[t*4+r2] = st[r2];
        }
        __builtin_amdgcn_s_setprio(0);

        if (kt == qg) {
            #pragma unroll
            for (int t = 0; t < 4; ++t)
                #pragma unroll
                for (int r = 0; r < 4; ++r)
                    if (16*t + 4*g + r > w*16 + q15) p[t*4+r] = -1e30f;
        }

        float psum = 0.f;
        #pragma unroll
        for (int i = 0; i < 16; ++i) { p[i] = __expf(p[i]); psum += p[i]; }
        psum += __shfl_xor(psum, 16);
        psum += __shfl_xor(psum, 32);
        lrow += psum;

        #pragma unroll
        for (int t = 0; t < 4; ++t) {
            unsigned r0, r1;
            asm("v_cvt_pk_bf16_f32 %0, %1, %2"
                : "=v"(r0) : "v"(p[t*4+0]), "v"(p[t*4+1]));
            asm("v_cvt_pk_bf16_f32 %0, %1, %2"
                : "=v"(r1) : "v"(p[t*4+2]), "v"(p[t*4+3]));
            int byte = q15*128 + ((32*t + 8*g) ^ ((q15&7)<<4));
            uint2 pk; pk.x = r0; pk.y = r1;
            *(uint2*)(plw + byte) = pk;
        }

        __builtin_amdgcn_s_setprio(1);
        #pragma unroll
        for (int c = 0; c < 2; ++c) {
            int pb = q15*128 + ((64*c + 16*g) ^ ((q15&7)<<4));
            short8 pf = *(const short8*)(plw + pb);
            #pragma unroll
            for (int dt = 0; dt < 4; ++dt) {
                int d = dt*16 + q15;
                int vb = d*128 + ((64*c + 16*g) ^ ((d&7)<<4));
                short8 vf = *(const short8*)(vt_ + vb);
                o[dt] = __builtin_amdgcn_mfma_f32_16x16x32_bf16(pf, vf, o[dt], 0, 0, 0);
            }
        }
        __builtin_amdgcn_s_setprio(0);

        if (!more) break;
        WRITEX(cur ^ 1);
        __syncthreads();
    }

    float inv = 1.f / lrow;
    #pragma unroll
    for (int r = 0; r < 4; ++r) {
        float li = __shfl(inv, 4*g + r);
        int qrow = q0 + w*16 + 4*g + r;
        #pragma unroll
        for (int dt = 0; dt < 4; ++dt) {
            O[((size_t)bh * S_ + qrow) * DH_ + dt*16 + q15] = f2bf(o[dt][r] * li);
        }
    }
}

// ---------------------------------------------------------------------------
// Scratch: ws = Qw|Kw|Vw (24 MiB) [+ wo^T at 24MB if ws_size allows];
// d_out = D0 (Wt_qkv then Vt) | xb (x_bf16).
// ---------------------------------------------------------------------------
extern "C" void kernel_launch(void* const* d_in, const int* in_sizes, int n_in,
                              void* d_out, int out_size, void* d_ws, size_t ws_size,
                              hipStream_t stream) {
    (void)in_sizes; (void)n_in; (void)out_size;
    const float* x  = (const float*)d_in[0];
    const float* wq = (const float*)d_in[1];
    const float* wk = (const float*)d_in[2];
    const float* wv = (const float*)d_in[3];
    const float* wo = (const float*)d_in[4];

    u16* Qw = (u16*)d_ws;
    u16* Kw = Qw + (size_t)M_ * F_;
    u16* Vw = Kw + (size_t)M_ * F_;

    u16* D0 = (u16*)d_out;
    u16* xb = D0 + (size_t)4*1024*1024;

    const bool bigws = ws_size >= ((size_t)27 << 20);
    u16* wot = bigws ? (u16*)((char*)d_ws + ((size_t)24 << 20)) : Vw;

    prep<<<dim3(bigws ? 3072 : 2816), 256, 0, stream>>>(
        x, wq, wk, wv, wo, xb, D0, wot);

    gemm_bf16<0><<<dim3(1536), 256, 0, stream>>>(
        xb, D0, (void*)Qw, (void*)Kw, (void*)Vw);

    vtrans<<<dim3(S_/64, B_*NH_), 256, 0, stream>>>(Vw, D0);
    if (!bigws)
        wtrans<<<dim3(16,16), 256, 0, stream>>>(wo, Vw);

    attn_v10<<<dim3(B_*NH_*(S_/64)), 256, 0, stream>>>(Qw, Kw, D0, Qw);

    gemm_bf16<2><<<dim3(512), 256, 0, stream>>>(
        Qw, wot, d_out, d_out, d_out);
}